// Round 10
// baseline (152.443 us; speedup 1.0000x reference)
//
#include <hip/hip_runtime.h>
#include <math.h>

typedef _Float16 v8h __attribute__((ext_vector_type(8)));
typedef float v4f __attribute__((ext_vector_type(4)));
typedef __fp16 h2 __attribute__((ext_vector_type(2)));

#define MFMA16(a, b, c) __builtin_amdgcn_mfma_f32_16x16x32_f16((a), (b), (c), 0, 0, 0)
#define ZV ((v4f){0.f, 0.f, 0.f, 0.f})

// swizzled row addressing: rows of 64 fp16 (128 B), XOR 16B-slot with row&7
#define TA64(row, colb) ((((row) * 128) + (colb)) ^ (((row) & 7) << 4))

__device__ __forceinline__ unsigned int pk_f16(float a, float b) {
    return __builtin_bit_cast(unsigned int, __builtin_amdgcn_cvt_pkrtz(a, b));
}
__device__ __forceinline__ unsigned int pkmax(unsigned int a, unsigned int b) {
    unsigned int r;
    asm("v_pk_max_f16 %0, %1, %2" : "=v"(r) : "v"(a), "v"(b));
    return r;
}

// ---------------------------------------------------------------- k_prep ----
// Wt[c][d]=fp16(Ww[d][c]); wallT[p][o][k]=fp16(w_p[k][o]); sc/bi fold BN.
__global__ __launch_bounds__(256) void k_prep(
    const float* __restrict__ tw, const float* __restrict__ pw,
    const float* __restrict__ gw,
    const float* __restrict__ Ww, const float* __restrict__ Wb,
    const float* __restrict__ gamma, const float* __restrict__ beta,
    const float* __restrict__ mean, const float* __restrict__ var,
    _Float16* __restrict__ Wt, _Float16* __restrict__ wallT,
    float* __restrict__ sc, float* __restrict__ bi)
{
    int gid = blockIdx.x * 256 + threadIdx.x;    // 4096 threads
    #pragma unroll
    for (int r = 0; r < 2; ++r) {
        int idx = r * 4096 + gid;                // 8192 = 64*128
        int d = idx >> 7, c = idx & 127;
        Wt[c * 64 + d] = (_Float16)Ww[idx];
    }
    #pragma unroll
    for (int r = 0; r < 6; ++r) {
        int idx = r * 4096 + gid;                // 24576 = 3*64*128
        int p = idx >> 13, rem = idx & 8191;
        int o = rem >> 7, k = rem & 127;
        const float* wm = (p == 0) ? tw : (p == 1) ? pw : gw;
        wallT[idx] = (_Float16)wm[k * 64 + o];
    }
    if (blockIdx.x == 0 && threadIdx.x < 128) {
        int c = threadIdx.x;
        float inv = gamma[c] * rsqrtf(var[c] + 1e-4f);
        sc[c] = inv;
        bi[c] = (Wb[c] - mean[c]) * inv + beta[c];
    }
}

// ---------------------------------------------------------------- k_proj ----
// fp16 MFMA projections, no barriers. 256 blocks x 512 thr = 8 waves x 16 tok.
// theta/phi: MFMA(A=x, B=w^T) -> D[token][o], per-wave LDS transpose -> 16B
// coalesced stores. g: swapped MFMA(A=w^T, B=x) -> D[o][token] -> direct
// stores (32B segments, L2 write-combines) into gT[b][64][4096].
__global__ __launch_bounds__(512, 4) void k_proj(
    const float* __restrict__ x, const _Float16* __restrict__ wallT,
    const float* __restrict__ tb, const float* __restrict__ pb,
    const float* __restrict__ gb,
    _Float16* __restrict__ theta, _Float16* __restrict__ phi,
    _Float16* __restrict__ gT)
{
    __shared__ __align__(16) _Float16 tsc[8][16 * 72];   // per-wave [16 tok][72]
    const int t = threadIdx.x;
    const int w = t >> 6, l = t & 63, h = l >> 4, lo = l & 15;
    const int tok0 = blockIdx.x * 128 + w * 16;
    _Float16* tw_l = &tsc[w][0];

    // x A/B frags (fp32 -> fp16): token row = lo, k = kc*32 + h*8
    v8h xA[4];
    #pragma unroll
    for (int kc = 0; kc < 4; ++kc) {
        const float* px = x + (size_t)(tok0 + lo) * 128 + kc * 32 + h * 8;
        float4 f0 = *(const float4*)(px);
        float4 f1 = *(const float4*)(px + 4);
        uint4 u;
        u.x = pk_f16(f0.x, f0.y); u.y = pk_f16(f0.z, f0.w);
        u.z = pk_f16(f1.x, f1.y); u.w = pk_f16(f1.z, f1.w);
        xA[kc] = __builtin_bit_cast(v8h, u);
    }

    #pragma unroll
    for (int p = 0; p < 2; ++p) {                // theta, phi
        const _Float16* wp = wallT + p * 8192;
        const float* bias = (p == 0) ? tb : pb;
        _Float16* dst = (p == 0) ? theta : phi;
        #pragma unroll
        for (int oc = 0; oc < 4; ++oc) {
            int o = oc * 16 + lo;
            v4f acc = ZV;
            #pragma unroll
            for (int kc = 0; kc < 4; ++kc) {
                v8h B = *(const v8h*)(wp + o * 128 + kc * 32 + h * 8);
                acc = MFMA16(xA[kc], B, acc);    // D[tok=4h+rr][o]
            }
            float bv = bias[o];
            #pragma unroll
            for (int rr = 0; rr < 4; ++rr)
                tw_l[(4 * h + rr) * 72 + o] = (_Float16)(acc[rr] + bv);
        }
        // read back per token, coalesced store (same-wave LDS ordering)
        int token = l >> 2, c = l & 3;
        v8h v0 = *(const v8h*)&tw_l[token * 72 + c * 16];
        v8h v1 = *(const v8h*)&tw_l[token * 72 + c * 16 + 8];
        _Float16* dp = dst + (size_t)(tok0 + token) * 64 + c * 16;
        *(v8h*)(dp) = v0;
        *(v8h*)(dp + 8) = v1;
    }
    // g: swapped -> D[o=oc*16+4h+rr][token=lo]
    {
        const _Float16* wp = wallT + 2 * 8192;
        int tokg = tok0 + lo;
        int bb = tokg >> 12, n = tokg & 4095;
        #pragma unroll
        for (int oc = 0; oc < 4; ++oc) {
            v4f acc = ZV;
            #pragma unroll
            for (int kc = 0; kc < 4; ++kc) {
                v8h A = *(const v8h*)(wp + (oc * 16 + lo) * 128 + kc * 32 + h * 8);
                acc = MFMA16(A, xA[kc], acc);
            }
            #pragma unroll
            for (int rr = 0; rr < 4; ++rr) {
                int o = oc * 16 + 4 * h + rr;
                gT[((size_t)bb * 64 + o) * 4096 + n] = (_Float16)(acc[rr] + gb[o]);
            }
        }
    }
}

// ---------------------------------------------------------------- k_attn ----
// Barrier-free flash attention + fused epilogue. Grid 512 blocks (b=bid&7 ->
// XCD-partitioned), 512 thr = 8 waves = qt(2: 32q) x kh(4: 1024-key range).
// Per 32-key step: phi + gv A-frags DIRECT global->reg (phi prefetched 1 step),
// swapped QK^T (q = lane&15 -> softmax lane-local), packed cross-lane max,
// deferred l-reduce, P via per-wave LDS (no sync). kh-combine once at end.
__global__ __launch_bounds__(512, 4) void k_attn(
    const _Float16* __restrict__ theta,
    const _Float16* __restrict__ phi,
    const _Float16* __restrict__ gT,
    const _Float16* __restrict__ Wt,
    const float* __restrict__ sc, const float* __restrict__ bi,
    const float* __restrict__ x, float* __restrict__ out)
{
    __shared__ __align__(16) _Float16 scr[8][32 * 64];   // 32KB: P / u / y
    __shared__ float zf[8 * 32];                         // 1KB: m + ln l

    const int t = threadIdx.x;
    const int w = t >> 6, l = t & 63, h = l >> 4, lo = l & 15;
    const int qt = w & 1, kh = w >> 1;
    const int bid = blockIdx.x;
    const int b = bid & 7, qb = bid >> 3;        // XCD k <- batch k (L2 locality)
    const size_t tok0 = (size_t)b * 4096 + qb * 64 + qt * 32;

    char* scrc = (char*)&scr[w][0];
    char* scr0 = (char*)&scr[0][0];

    v8h thA[2][2];                               // B-frags: col=q=lo
    #pragma unroll
    for (int f = 0; f < 2; ++f)
        #pragma unroll
        for (int kc = 0; kc < 2; ++kc)
            thA[f][kc] = *(const v8h*)(theta +
                (tok0 + f * 16 + lo) * 64 + kc * 32 + h * 8);

    const _Float16* phb = phi + (size_t)b * 4096 * 64;
    const _Float16* gvb = gT + (size_t)b * 64 * 4096;

    v4f yacc[2][4];                              // y[q=f*16+lo][d=dt*16+4h+rr]
    #pragma unroll
    for (int f = 0; f < 2; ++f)
        #pragma unroll
        for (int dt = 0; dt < 4; ++dt) yacc[f][dt] = ZV;
    float mrow[2] = {-INFINITY, -INFINITY}, lpart[2] = {0.f, 0.f};

    const int kbase0 = kh * 1024;
    v8h pfP[2][2];                               // phi A-frags, 1-step prefetch
    #pragma unroll
    for (int s = 0; s < 2; ++s)
        #pragma unroll
        for (int kc = 0; kc < 2; ++kc)
            pfP[s][kc] = *(const v8h*)(phb +
                (size_t)(kbase0 + s * 16 + lo) * 64 + kc * 32 + h * 8);

    for (int kt = 0; kt < 32; ++kt) {
        const int kb = kbase0 + kt * 32;
        v8h aP00 = pfP[0][0], aP01 = pfP[0][1];
        v8h aP10 = pfP[1][0], aP11 = pfP[1][1];
        // ---- QK^T: S[f][s][rr] = logit(key = kb + s*16+4h+rr, q = f*16+lo)
        v4f S[2][2];
        __builtin_amdgcn_s_setprio(1);
        #pragma unroll
        for (int f = 0; f < 2; ++f) {
            v4f c0 = MFMA16(aP00, thA[f][0], ZV);
            S[f][0] = MFMA16(aP01, thA[f][1], c0);
            v4f c1 = MFMA16(aP10, thA[f][0], ZV);
            S[f][1] = MFMA16(aP11, thA[f][1], c1);
        }
        __builtin_amdgcn_s_setprio(0);
        if (kt < 31) {                           // prefetch next phi frags
            #pragma unroll
            for (int s = 0; s < 2; ++s)
                #pragma unroll
                for (int kc = 0; kc < 2; ++kc)
                    pfP[s][kc] = *(const v8h*)(phb +
                        (size_t)(kb + 32 + s * 16 + lo) * 64 + kc * 32 + h * 8);
        }
        // ---- gv A-frags for this step (consumed after softmax)
        v8h gv[4];
        #pragma unroll
        for (int dt = 0; dt < 4; ++dt)
            gv[dt] = *(const v8h*)(gvb + (size_t)(dt * 16 + lo) * 4096 + kb + h * 8);
        // ---- softmax: in-lane tree + packed 2-shfl cross-lane max
        float vm[2];
        #pragma unroll
        for (int f = 0; f < 2; ++f)
            vm[f] = fmaxf(fmaxf(fmaxf(S[f][0][0], S[f][0][1]),
                                fmaxf(S[f][0][2], S[f][0][3])),
                          fmaxf(fmaxf(S[f][1][0], S[f][1][1]),
                                fmaxf(S[f][1][2], S[f][1][3])));
        unsigned int pm = pk_f16(vm[0], vm[1]);
        pm = pkmax(pm, (unsigned int)__shfl_xor((int)pm, 16));
        pm = pkmax(pm, (unsigned int)__shfl_xor((int)pm, 32));
        h2 mh = __builtin_bit_cast(h2, pm);
        float vmr[2] = {(float)mh[0], (float)mh[1]};
        bool ok = (vmr[0] <= mrow[0] + 8.0f) && (vmr[1] <= mrow[1] + 8.0f);
        if (!__all(ok)) {                        // defer-max (THR=8)
            #pragma unroll
            for (int f = 0; f < 2; ++f) {
                float mn = fmaxf(mrow[f], vmr[f]);
                float aa = __expf(mrow[f] - mn); // 0 on first step
                mrow[f] = mn;
                lpart[f] *= aa;
                #pragma unroll
                for (int dt = 0; dt < 4; ++dt)
                    #pragma unroll
                    for (int rr = 0; rr < 4; ++rr)
                        yacc[f][dt][rr] *= aa;   // lane-local: all q = lo
            }
        }
        #pragma unroll
        for (int f = 0; f < 2; ++f) {
            float p[2][4];
            float ps = 0.f;
            #pragma unroll
            for (int s = 0; s < 2; ++s)
                #pragma unroll
                for (int rr = 0; rr < 4; ++rr) {
                    p[s][rr] = __expf(S[f][s][rr] - mrow[f]);
                    ps += p[s][rr];
                }
            lpart[f] += ps;                      // cross-lane reduce deferred
            uint2 u0, u1;
            u0.x = pk_f16(p[0][0], p[0][1]); u0.y = pk_f16(p[0][2], p[0][3]);
            u1.x = pk_f16(p[1][0], p[1][1]); u1.y = pk_f16(p[1][2], p[1][3]);
            *(uint2*)(scrc + TA64(f * 16 + lo, h * 8)) = u0;
            *(uint2*)(scrc + TA64(f * 16 + lo, 32 + h * 8)) = u1;
        }
        // ---- PV: B-frag P[q=lo][k], A = gv rows d
        v8h pA[2];
        #pragma unroll
        for (int f = 0; f < 2; ++f)
            pA[f] = *(const v8h*)(scrc + TA64(f * 16 + lo, h * 16));
        __builtin_amdgcn_s_setprio(1);
        #pragma unroll
        for (int f = 0; f < 2; ++f)
            #pragma unroll
            for (int dt = 0; dt < 4; ++dt)
                yacc[f][dt] = MFMA16(gv[dt], pA[f], yacc[f][dt]);
        __builtin_amdgcn_s_setprio(0);
    }

    // ---- final l reduce (once), write u = y/l (fp16) + z = m + ln l
    float lrow[2], inv[2];
    #pragma unroll
    for (int f = 0; f < 2; ++f) {
        float s = lpart[f];
        s += __shfl_xor(s, 16);
        s += __shfl_xor(s, 32);
        lrow[f] = s;
        inv[f] = 1.0f / s;
    }
    unsigned int uw[16];
    #pragma unroll
    for (int f = 0; f < 2; ++f)
        #pragma unroll
        for (int dt = 0; dt < 4; ++dt) {
            uw[f * 8 + dt * 2 + 0] = pk_f16(yacc[f][dt][0] * inv[f],
                                            yacc[f][dt][1] * inv[f]);
            uw[f * 8 + dt * 2 + 1] = pk_f16(yacc[f][dt][2] * inv[f],
                                            yacc[f][dt][3] * inv[f]);
        }
    #pragma unroll
    for (int j = 0; j < 4; ++j) {
        uint4 u;
        u.x = uw[4 * j]; u.y = uw[4 * j + 1];
        u.z = uw[4 * j + 2]; u.w = uw[4 * j + 3];
        *(uint4*)(scrc + l * 64 + j * 16) = u;
    }
    zf[w * 32 + lo] = mrow[0] + __logf(lrow[0]);
    zf[w * 32 + 16 + lo] = mrow[1] + __logf(lrow[1]);
    __syncthreads();
    if (w >= 2) return;

    // ---- combine 4 kh partials (slots kp*2 + qt; this wave: qt = w)
    float zq[4][2];
    #pragma unroll
    for (int kp = 0; kp < 4; ++kp) {
        int ws = kp * 2 + qt;
        zq[kp][0] = zf[ws * 32 + lo];
        zq[kp][1] = zf[ws * 32 + 16 + lo];
    }
    float zmx[2], wsum[2] = {0.f, 0.f};
    #pragma unroll
    for (int f = 0; f < 2; ++f)
        zmx[f] = fmaxf(fmaxf(zq[0][f], zq[1][f]), fmaxf(zq[2][f], zq[3][f]));
    float yfin[2][4][4];
    #pragma unroll
    for (int f = 0; f < 2; ++f)
        #pragma unroll
        for (int dt = 0; dt < 4; ++dt)
            #pragma unroll
            for (int rr = 0; rr < 4; ++rr) yfin[f][dt][rr] = 0.f;
    #pragma unroll
    for (int kp = 0; kp < 4; ++kp) {
        int ws = kp * 2 + qt;
        v8h c[4];
        #pragma unroll
        for (int j = 0; j < 4; ++j)
            c[j] = *(const v8h*)(scr0 + ws * 4096 + l * 64 + j * 16);
        float wk[2];
        #pragma unroll
        for (int f = 0; f < 2; ++f) {
            wk[f] = __expf(zq[kp][f] - zmx[f]);
            wsum[f] += wk[f];
        }
        #pragma unroll
        for (int f = 0; f < 2; ++f)
            #pragma unroll
            for (int dt = 0; dt < 4; ++dt)
                #pragma unroll
                for (int rr = 0; rr < 4; ++rr) {
                    int e = f * 16 + dt * 4 + rr;
                    yfin[f][dt][rr] += wk[f] * (float)c[e >> 3][e & 7];
                }
    }
    // ---- normalized y -> scr (swizzled), read back as epilogue A-frags
    #pragma unroll
    for (int f = 0; f < 2; ++f) {
        float iv = 1.0f / wsum[f];
        #pragma unroll
        for (int dt = 0; dt < 4; ++dt) {
            uint2 uu;
            uu.x = pk_f16(yfin[f][dt][0] * iv, yfin[f][dt][1] * iv);
            uu.y = pk_f16(yfin[f][dt][2] * iv, yfin[f][dt][3] * iv);
            *(uint2*)(scrc + TA64(f * 16 + lo, dt * 32 + h * 8)) = uu;
        }
    }
    v8h yA[2][2];
    #pragma unroll
    for (int f = 0; f < 2; ++f)
        #pragma unroll
        for (int kc = 0; kc < 2; ++kc)
            yA[f][kc] = *(const v8h*)(scrc + TA64(f * 16 + lo,
                                                  kc * 64 + h * 16));
    // ---- epilogue: wy = y @ W^T -> BN + residual
    const float* xb = x + tok0 * 128;
    float* ob = out + tok0 * 128;
    #pragma unroll
    for (int ct = 0; ct < 8; ++ct) {
        int c = ct * 16 + lo;
        v8h wB0 = *(const v8h*)(Wt + c * 64 + h * 8);
        v8h wB1 = *(const v8h*)(Wt + c * 64 + 32 + h * 8);
        float scc = sc[c], bic = bi[c];
        #pragma unroll
        for (int f = 0; f < 2; ++f) {
            v4f wy = MFMA16(yA[f][0], wB0, ZV);
            wy = MFMA16(yA[f][1], wB1, wy);
            #pragma unroll
            for (int rr = 0; rr < 4; ++rr) {
                int m = f * 16 + 4 * h + rr;
                ob[(size_t)m * 128 + c] =
                    wy[rr] * scc + bic + xb[(size_t)m * 128 + c];
            }
        }
    }
}

// ------------------------------------------------------------------ launch --
extern "C" void kernel_launch(void* const* d_in, const int* in_sizes, int n_in,
                              void* d_out, int out_size, void* d_ws, size_t ws_size,
                              hipStream_t stream) {
    const float* x     = (const float*)d_in[0];
    const float* tw    = (const float*)d_in[1];
    const float* tb    = (const float*)d_in[2];
    const float* pw    = (const float*)d_in[3];
    const float* pb    = (const float*)d_in[4];
    const float* gw    = (const float*)d_in[5];
    const float* gb    = (const float*)d_in[6];
    const float* Ww    = (const float*)d_in[7];
    const float* Wb    = (const float*)d_in[8];
    const float* gamma = (const float*)d_in[9];
    const float* beta  = (const float*)d_in[10];
    const float* mean  = (const float*)d_in[11];
    const float* var   = (const float*)d_in[12];

    char* ws = (char*)d_ws;
    _Float16* theta = (_Float16*)ws;                       // 4 MB
    _Float16* phi   = (_Float16*)(ws + (4u << 20));        // 4 MB
    _Float16* gT    = (_Float16*)(ws + (8u << 20));        // 4 MB
    _Float16* Wt    = (_Float16*)(ws + (12u << 20));       // 16 KB
    _Float16* wallT = (_Float16*)(ws + (12u << 20) + (1u << 16));  // 48 KB
    float* sc       = (float*)(ws + (12u << 20) + (2u << 16));
    float* bi       = sc + 128;

    k_prep<<<16, 256, 0, stream>>>(tw, pw, gw, Ww, Wb, gamma, beta, mean, var,
                                   Wt, wallT, sc, bi);
    k_proj<<<256, 512, 0, stream>>>(x, wallT, tb, pb, gb, theta, phi, gT);
    k_attn<<<512, 512, 0, stream>>>(theta, phi, gT, Wt, sc, bi,
                                    x, (float*)d_out);
}

// Round 11
// 103.152 us; speedup vs baseline: 1.4778x; 1.4778x over previous
//
#include <hip/hip_runtime.h>
#include <math.h>

typedef _Float16 v8h __attribute__((ext_vector_type(8)));
typedef float v4f __attribute__((ext_vector_type(4)));
typedef float v16f __attribute__((ext_vector_type(16)));

#define MFMA32(a, b, c) __builtin_amdgcn_mfma_f32_32x32x16_f16((a), (b), (c), 0, 0, 0)
#define MFMA16(a, b, c) __builtin_amdgcn_mfma_f32_16x16x32_f16((a), (b), (c), 0, 0, 0)
#define ZV4 ((v4f){0.f, 0.f, 0.f, 0.f})

// swizzled tile addressing (byte offsets)
#define TA64(row, colb)  ((((row) * 128) + (colb)) ^ (((row) & 7) << 4))
#define TA128(row, colb) ((((row) * 256) + (colb)) ^ (((row) & 15) << 4))

__device__ __forceinline__ unsigned int pk_f16(float a, float b) {
    return __builtin_bit_cast(unsigned int, __builtin_amdgcn_cvt_pkrtz(a, b));
}
// v_permlane32_swap_b32: a' = [a_row0, b_row0], b' = [a_row1, b_row1]
__device__ __forceinline__ void pl32swap(unsigned int& a, unsigned int& b) {
    asm("v_permlane32_swap_b32 %0, %1" : "+v"(a), "+v"(b));
}

// ---------------------------------------------------------------- k_prep ----
__global__ __launch_bounds__(256) void k_prep(
    const float* __restrict__ tw, const float* __restrict__ pw,
    const float* __restrict__ gw,
    const float* __restrict__ Ww, const float* __restrict__ Wb,
    const float* __restrict__ gamma, const float* __restrict__ beta,
    const float* __restrict__ mean, const float* __restrict__ var,
    _Float16* __restrict__ Wt, _Float16* __restrict__ wallT,
    float* __restrict__ sc, float* __restrict__ bi)
{
    int gid = blockIdx.x * 256 + threadIdx.x;    // 4096 threads
    #pragma unroll
    for (int r = 0; r < 2; ++r) {
        int idx = r * 4096 + gid;                // 8192 = 64*128
        int d = idx >> 7, c = idx & 127;
        Wt[c * 64 + d] = (_Float16)Ww[idx];      // Wt[c][d] = W_w[d][c]
    }
    #pragma unroll
    for (int r = 0; r < 6; ++r) {
        int idx = r * 4096 + gid;                // 24576 = 3*64*128
        int p = idx >> 13, rem = idx & 8191;
        int o = rem >> 7, k = rem & 127;
        const float* wm = (p == 0) ? tw : (p == 1) ? pw : gw;
        wallT[idx] = (_Float16)wm[k * 64 + o];
    }
    if (blockIdx.x == 0 && threadIdx.x < 128) {
        int c = threadIdx.x;
        float inv = gamma[c] * rsqrtf(var[c] + 1e-4f);
        sc[c] = inv;
        bi[c] = (Wb[c] - mean[c]) * inv + beta[c];
    }
}

// ---------------------------------------------------------------- k_proj ----
// fp16 MFMA projections, no barriers (r10-proven). 256 blocks x 512 threads.
__global__ __launch_bounds__(512, 4) void k_proj(
    const float* __restrict__ x, const _Float16* __restrict__ wallT,
    const float* __restrict__ tb, const float* __restrict__ pb,
    const float* __restrict__ gb,
    _Float16* __restrict__ theta, _Float16* __restrict__ phi,
    _Float16* __restrict__ gT)
{
    __shared__ __align__(16) _Float16 tsc[8][16 * 72];
    const int t = threadIdx.x;
    const int w = t >> 6, l = t & 63, h = l >> 4, lo = l & 15;
    const int tok0 = blockIdx.x * 128 + w * 16;
    _Float16* tw_l = &tsc[w][0];

    v8h xA[4];
    #pragma unroll
    for (int kc = 0; kc < 4; ++kc) {
        const float* px = x + (size_t)(tok0 + lo) * 128 + kc * 32 + h * 8;
        float4 f0 = *(const float4*)(px);
        float4 f1 = *(const float4*)(px + 4);
        uint4 u;
        u.x = pk_f16(f0.x, f0.y); u.y = pk_f16(f0.z, f0.w);
        u.z = pk_f16(f1.x, f1.y); u.w = pk_f16(f1.z, f1.w);
        xA[kc] = __builtin_bit_cast(v8h, u);
    }

    #pragma unroll
    for (int p = 0; p < 2; ++p) {                // theta, phi
        const _Float16* wp = wallT + p * 8192;
        const float* bias = (p == 0) ? tb : pb;
        _Float16* dst = (p == 0) ? theta : phi;
        #pragma unroll
        for (int oc = 0; oc < 4; ++oc) {
            int o = oc * 16 + lo;
            v4f acc = ZV4;
            #pragma unroll
            for (int kc = 0; kc < 4; ++kc) {
                v8h B = *(const v8h*)(wp + o * 128 + kc * 32 + h * 8);
                acc = MFMA16(xA[kc], B, acc);
            }
            float bv = bias[o];
            #pragma unroll
            for (int rr = 0; rr < 4; ++rr)
                tw_l[(4 * h + rr) * 72 + o] = (_Float16)(acc[rr] + bv);
        }
        int token = l >> 2, c = l & 3;
        v8h v0 = *(const v8h*)&tw_l[token * 72 + c * 16];
        v8h v1 = *(const v8h*)&tw_l[token * 72 + c * 16 + 8];
        _Float16* dp = dst + (size_t)(tok0 + token) * 64 + c * 16;
        *(v8h*)(dp) = v0;
        *(v8h*)(dp + 8) = v1;
    }
    {
        const _Float16* wp = wallT + 2 * 8192;
        int tokg = tok0 + lo;
        int bb = tokg >> 12, n = tokg & 4095;
        #pragma unroll
        for (int oc = 0; oc < 4; ++oc) {
            v4f acc = ZV4;
            #pragma unroll
            for (int kc = 0; kc < 4; ++kc) {
                v8h A = *(const v8h*)(wp + (oc * 16 + lo) * 128 + kc * 32 + h * 8);
                acc = MFMA16(A, xA[kc], acc);
            }
            #pragma unroll
            for (int rr = 0; rr < 4; ++rr) {
                int o = oc * 16 + 4 * h + rr;
                gT[((size_t)bb * 64 + o) * 4096 + n] = (_Float16)(acc[rr] + gb[o]);
            }
        }
    }
}

// ---------------------------------------------------------------- k_attn ----
// Flash attention, 32x32x16 MFMA, in-register P (permlane32_swap), LDS-staged
// K/V with register prefetch. Grid 512 blocks (b = bid&7: XCD-partitioned),
// 512 thr = 8 waves = qt(2: 32 q) x kh(4: 32-key quarter of each 128-key tile).
// Swapped QK^T: D col = q = lane&31 -> softmax fully lane-local (1 shfl).
// S->PV-B redistribution: 8 cvt_pk + 4 v_permlane32_swap, zero LDS.
// End: 4-way kh combine (partials in reused stage LDS) + 32x32 epilogue.
__global__ __launch_bounds__(512, 4) void k_attn(
    const _Float16* __restrict__ theta,
    const _Float16* __restrict__ phi,
    const _Float16* __restrict__ gT,
    const _Float16* __restrict__ Wt,
    const float* __restrict__ sc, const float* __restrict__ bi,
    const float* __restrict__ x, float* __restrict__ out)
{
    __shared__ __align__(16) _Float16 ldsbuf[16384];     // 32KB: ph|gv, partials
    __shared__ float zf[8 * 32];                         // 1KB: m + ln l

    const int t = threadIdx.x;
    const int w = t >> 6, l = t & 63, q32 = l & 31, hi2 = l >> 5;
    const int qt = w & 1, kh = w >> 1;
    const int bid = blockIdx.x;
    const int b = bid & 7, qb = bid >> 3;
    const size_t tok0 = (size_t)b * 4096 + qb * 64;      // block q-base
    const int tokA = (int)(qb * 64) + qt * 32;           // wave q-tile (in-batch)

    char* phL = (char*)ldsbuf;                           // [128 keys][64] TA64
    char* gvL = (char*)(ldsbuf + 8192);                  // [64 d][128 keys] TA128

    // theta B-frags: col = q = q32, k = kc*16 + hi2*8 + j
    v8h thB[4];
    #pragma unroll
    for (int kc = 0; kc < 4; ++kc)
        thB[kc] = *(const v8h*)(theta +
            (tok0 + qt * 32 + q32) * 64 + kc * 16 + hi2 * 8);

    const _Float16* phb = phi + (size_t)b * 4096 * 64;
    const _Float16* gvb = gT + (size_t)b * 64 * 4096;

    v16f yacc[2];                                        // [df] col=q, row=d
    #pragma unroll
    for (int df = 0; df < 2; ++df)
        #pragma unroll
        for (int r = 0; r < 16; ++r) yacc[df][r] = 0.f;
    float mrow = -INFINITY, lpart = 0.f;

    // hoisted swizzled read addresses (loop-invariant)
    int qkRd[4], gvRd[2][2];
    #pragma unroll
    for (int kc = 0; kc < 4; ++kc)
        qkRd[kc] = TA64(kh * 32 + q32, (kc * 16 + hi2 * 8) * 2);
    #pragma unroll
    for (int df = 0; df < 2; ++df)
        #pragma unroll
        for (int s = 0; s < 2; ++s)
            gvRd[df][s] = TA128(df * 32 + q32, (kh * 32 + s * 16 + hi2 * 8) * 2);

    // staging: ph 2 chunks/thread (rows t>>3, +64), gv 2 (rows t>>4, +32)
    const int phA0 = TA64(t >> 3, (t & 7) * 16);
    const int phA1 = TA64((t >> 3) + 64, (t & 7) * 16);
    const int gvA0 = TA128(t >> 4, (t & 15) * 16);
    const int gvA1 = TA128((t >> 4) + 32, (t & 15) * 16);
    const _Float16* pPh = phb + (size_t)(t >> 3) * 64 + (t & 7) * 8;
    const _Float16* pGv = gvb + (size_t)(t >> 4) * 4096 + (t & 15) * 8;

    v8h pf0 = *(const v8h*)(pPh);
    v8h pf1 = *(const v8h*)(pPh + 64 * 64);
    v8h pf2 = *(const v8h*)(pGv);
    v8h pf3 = *(const v8h*)(pGv + (size_t)32 * 4096);
    pPh += 8192; pGv += 128;

    for (int kt = 0; kt < 32; ++kt) {
        __syncthreads();                                 // prev tile consumed
        *(v8h*)(phL + phA0) = pf0;
        *(v8h*)(phL + phA1) = pf1;
        *(v8h*)(gvL + gvA0) = pf2;
        *(v8h*)(gvL + gvA1) = pf3;
        __syncthreads();
        if (kt < 31) {                                   // prefetch next tile
            pf0 = *(const v8h*)(pPh);
            pf1 = *(const v8h*)(pPh + 64 * 64);
            pf2 = *(const v8h*)(pGv);
            pf3 = *(const v8h*)(pGv + (size_t)32 * 4096);
            pPh += 8192; pGv += 128;
        }
        // ---- QK^T: S[reg] = logit(key kh*32 + (reg&3)+8*(reg>>2)+4*hi2, q32)
        v16f S;
        #pragma unroll
        for (int r = 0; r < 16; ++r) S[r] = 0.f;
        __builtin_amdgcn_s_setprio(1);
        #pragma unroll
        for (int kc = 0; kc < 4; ++kc) {
            v8h A = *(const v8h*)(phL + qkRd[kc]);
            S = MFMA32(A, thB[kc], S);
        }
        __builtin_amdgcn_s_setprio(0);
        // ---- softmax: in-lane tree + 1 cross shfl (partner has other 16 keys)
        float m0 = fmaxf(fmaxf(S[0], S[1]), fmaxf(S[2], S[3]));
        float m1 = fmaxf(fmaxf(S[4], S[5]), fmaxf(S[6], S[7]));
        float m2 = fmaxf(fmaxf(S[8], S[9]), fmaxf(S[10], S[11]));
        float m3 = fmaxf(fmaxf(S[12], S[13]), fmaxf(S[14], S[15]));
        float vmax = fmaxf(fmaxf(m0, m1), fmaxf(m2, m3));
        vmax = fmaxf(vmax, __shfl_xor(vmax, 32));
        if (!__all(vmax <= mrow + 8.0f)) {               // defer-max (THR=8)
            float mn = fmaxf(mrow, vmax);
            float aa = __expf(mrow - mn);                // 0 on first tile
            mrow = mn;
            lpart *= aa;
            #pragma unroll
            for (int df = 0; df < 2; ++df)
                #pragma unroll
                for (int r = 0; r < 16; ++r)
                    yacc[df][r] *= aa;                   // all cols = q32
        }
        float psum = 0.f;
        #pragma unroll
        for (int r = 0; r < 16; ++r) {
            S[r] = __expf(S[r] - mrow);
            psum += S[r];
        }
        lpart += psum;                                   // cross-lane deferred
        // ---- P -> PV B-frags in-register (cvt_pk + permlane32_swap)
        unsigned int W0 = pk_f16(S[0], S[1]),  W1 = pk_f16(S[2], S[3]);
        unsigned int W2 = pk_f16(S[4], S[5]),  W3 = pk_f16(S[6], S[7]);
        unsigned int W4 = pk_f16(S[8], S[9]),  W5 = pk_f16(S[10], S[11]);
        unsigned int W6 = pk_f16(S[12], S[13]), W7 = pk_f16(S[14], S[15]);
        pl32swap(W0, W2); pl32swap(W1, W3);              // keys 0-15
        pl32swap(W4, W6); pl32swap(W5, W7);              // keys 16-31
        uint4 ub1; ub1.x = W0; ub1.y = W1; ub1.z = W2; ub1.w = W3;
        uint4 ub2; ub2.x = W4; ub2.y = W5; ub2.z = W6; ub2.w = W7;
        v8h pB[2] = {__builtin_bit_cast(v8h, ub1), __builtin_bit_cast(v8h, ub2)};
        // ---- PV: A = gv rows d (df half), k = 16 keys per MFMA
        __builtin_amdgcn_s_setprio(1);
        #pragma unroll
        for (int df = 0; df < 2; ++df)
            #pragma unroll
            for (int s = 0; s < 2; ++s) {
                v8h A = *(const v8h*)(gvL + gvRd[df][s]);
                yacc[df] = MFMA32(A, pB[s], yacc[df]);
            }
        __builtin_amdgcn_s_setprio(0);
    }

    // ---- write partials: u = y/l (fp16, 32/lane) into reused stage LDS
    __syncthreads();                                     // all tile reads done
    float lrow = lpart + __shfl_xor(lpart, 32);
    float inv = 1.0f / lrow;
    {
        char* slot = (char*)ldsbuf + w * 4096 + l * 64;
        #pragma unroll
        for (int j = 0; j < 4; ++j) {
            int df = j >> 1, r0 = (j & 1) * 8;
            uint4 u;
            u.x = pk_f16(yacc[df][r0 + 0] * inv, yacc[df][r0 + 1] * inv);
            u.y = pk_f16(yacc[df][r0 + 2] * inv, yacc[df][r0 + 3] * inv);
            u.z = pk_f16(yacc[df][r0 + 4] * inv, yacc[df][r0 + 5] * inv);
            u.w = pk_f16(yacc[df][r0 + 6] * inv, yacc[df][r0 + 7] * inv);
            *(uint4*)(slot + (j * 16 ^ ((l & 3) << 4))) = u;
        }
        zf[w * 32 + q32] = mrow + __logf(lrow);
    }
    __syncthreads();
    if (w >= 2) return;

    // ---- combine 4 kh partials (slots kp*2 + qt; this wave: qt = w)
    float zq[4];
    #pragma unroll
    for (int kp = 0; kp < 4; ++kp) zq[kp] = zf[(kp * 2 + qt) * 32 + q32];
    float zmx = fmaxf(fmaxf(zq[0], zq[1]), fmaxf(zq[2], zq[3]));
    float wsum = 0.f;
    float yfin[2][16];
    #pragma unroll
    for (int df = 0; df < 2; ++df)
        #pragma unroll
        for (int r = 0; r < 16; ++r) yfin[df][r] = 0.f;
    #pragma unroll
    for (int kp = 0; kp < 4; ++kp) {
        char* slot = (char*)ldsbuf + (kp * 2 + qt) * 4096 + l * 64;
        float wk = __expf(zq[kp] - zmx);
        wsum += wk;
        #pragma unroll
        for (int j = 0; j < 4; ++j) {
            v8h c = *(const v8h*)(slot + (j * 16 ^ ((l & 3) << 4)));
            int df = j >> 1, r0 = (j & 1) * 8;
            #pragma unroll
            for (int e = 0; e < 8; ++e)
                yfin[df][r0 + e] += wk * (float)c[e];
        }
    }
    float nrm = 1.0f / wsum;
    // ---- epilogue A-frags: y rows q, k = d (cvt_pk + permlane32_swap)
    v8h yA[4];
    #pragma unroll
    for (int kc = 0; kc < 4; ++kc) {
        int df = kc >> 1, r0 = (kc & 1) * 8;
        unsigned int Wa = pk_f16(yfin[df][r0 + 0] * nrm, yfin[df][r0 + 1] * nrm);
        unsigned int Wb2 = pk_f16(yfin[df][r0 + 2] * nrm, yfin[df][r0 + 3] * nrm);
        unsigned int Wc = pk_f16(yfin[df][r0 + 4] * nrm, yfin[df][r0 + 5] * nrm);
        unsigned int Wd = pk_f16(yfin[df][r0 + 6] * nrm, yfin[df][r0 + 7] * nrm);
        pl32swap(Wa, Wc); pl32swap(Wb2, Wd);
        uint4 u; u.x = Wa; u.y = Wb2; u.z = Wc; u.w = Wd;
        yA[kc] = __builtin_bit_cast(v8h, u);
    }
    // ---- wy = y @ W -> BN + residual; B col = c (Wt is c-major fp16)
    const float* xb = x + (size_t)b * 4096 * 128;
    float* ob = out + (size_t)b * 4096 * 128;
    #pragma unroll
    for (int cf = 0; cf < 4; ++cf) {
        int c = cf * 32 + q32;
        v16f wy;
        #pragma unroll
        for (int r = 0; r < 16; ++r) wy[r] = 0.f;
        #pragma unroll
        for (int kc = 0; kc < 4; ++kc) {
            v8h wB = *(const v8h*)(Wt + c * 64 + kc * 16 + hi2 * 8);
            wy = MFMA32(yA[kc], wB, wy);
        }
        float scc = sc[c], bic = bi[c];
        #pragma unroll
        for (int r = 0; r < 16; ++r) {
            int qrow = (r & 3) + 8 * (r >> 2) + 4 * hi2;
            size_t off = (size_t)(tokA + qrow) * 128 + c;
            ob[off] = wy[r] * scc + bic + xb[off];
        }
    }
}

// ------------------------------------------------------------------ launch --
extern "C" void kernel_launch(void* const* d_in, const int* in_sizes, int n_in,
                              void* d_out, int out_size, void* d_ws, size_t ws_size,
                              hipStream_t stream) {
    const float* x     = (const float*)d_in[0];
    const float* tw    = (const float*)d_in[1];
    const float* tb    = (const float*)d_in[2];
    const float* pw    = (const float*)d_in[3];
    const float* pb    = (const float*)d_in[4];
    const float* gw    = (const float*)d_in[5];
    const float* gb    = (const float*)d_in[6];
    const float* Ww    = (const float*)d_in[7];
    const float* Wb    = (const float*)d_in[8];
    const float* gamma = (const float*)d_in[9];
    const float* beta  = (const float*)d_in[10];
    const float* mean  = (const float*)d_in[11];
    const float* var   = (const float*)d_in[12];

    char* ws = (char*)d_ws;
    _Float16* theta = (_Float16*)ws;                       // 4 MB
    _Float16* phi   = (_Float16*)(ws + (4u << 20));        // 4 MB
    _Float16* gT    = (_Float16*)(ws + (8u << 20));        // 4 MB
    _Float16* Wt    = (_Float16*)(ws + (12u << 20));       // 16 KB
    _Float16* wallT = (_Float16*)(ws + (12u << 20) + (1u << 16));  // 48 KB
    float* sc       = (float*)(ws + (12u << 20) + (2u << 16));
    float* bi       = sc + 128;

    k_prep<<<16, 256, 0, stream>>>(tw, pw, gw, Ww, Wb, gamma, beta, mean, var,
                                   Wt, wallT, sc, bi);
    k_proj<<<256, 512, 0, stream>>>(x, wallT, tb, pb, gb, theta, phi, gT);
    k_attn<<<512, 512, 0, stream>>>(theta, phi, gT, Wt, sc, bi,
                                    x, (float*)d_out);
}